// Round 6
// baseline (304.328 us; speedup 1.0000x reference)
//
#include <hip/hip_runtime.h>

// B=128, S=1024, H=256
#define Bb 128
#define Ss 1024
#define Hh 256
#define NEGF 1e9f

typedef short bf16x8 __attribute__((ext_vector_type(8)));
typedef float f32x4 __attribute__((ext_vector_type(4)));

__device__ __forceinline__ short f2bf(float f) {
    union { float f; unsigned u; } c; c.f = f;
    return (short)((c.u + 0x8000u) >> 16);
}

// packed fp32->bf16 (RNE), 1 instr per 2 elements
__device__ __forceinline__ unsigned cvt_pk_bf16(float a, float b) {
    unsigned r;
    asm("v_cvt_pk_bf16_f32 %0, %1, %2" : "=v"(r) : "v"(a), "v"(b));
    return r;
}

__device__ __forceinline__ float fast_tanh(float x) {
    float cl = fminf(fmaxf(x, -10.f), 10.f);
    float e = __expf(2.f * cl);
    return (e - 1.f) * __builtin_amdgcn_rcpf(e + 1.f);
}

// async global->LDS, 16B per lane; dest = (wave-uniform) lds base + lane*16
__device__ __forceinline__ void stage16(const void* g, short* l) {
    __builtin_amdgcn_global_load_lds((const __attribute__((address_space(1))) void*)g,
                                     (__attribute__((address_space(3))) void*)l, 16, 0, 0);
}

// counted vmcnt wait: gfx9 encoding vm[3:0]|exp[6:4]|lgkm[11:8] (exp,lgkm = no-wait)
#define WAITVM(N) { __builtin_amdgcn_s_waitcnt(0x0F70 | (N)); __builtin_amdgcn_sched_barrier(0); }

// ---------------- prep: wg,wp -> bf16 (blocks 0..255); qbias_g (blocks 256..383)
__global__ __launch_bounds__(256) void prep_kernel(const float* __restrict__ wg,
                                                   const float* __restrict__ wp,
                                                   const float* __restrict__ query,
                                                   const float* __restrict__ wqg,
                                                   const float* __restrict__ bg,
                                                   short* __restrict__ wgb,
                                                   short* __restrict__ wpb,
                                                   float* __restrict__ qbias_g) {
    int blk = blockIdx.x, t = threadIdx.x;
    if (blk < 256) {
        int i = blk * 256 + t;
        wgb[i] = f2bf(wg[i]);
        wpb[i] = f2bf(wp[i]);
    } else {
        int b = blk - 256;
        const float4* qr = (const float4*)(query + b * Hh);
        const float4* wr = (const float4*)(wqg + t * Hh);
        float acc = 0.f;
#pragma unroll 8
        for (int i = 0; i < Hh / 4; ++i) {
            float4 q4 = qr[i], w4 = wr[i];
            acc += q4.x * w4.x + q4.y * w4.y + q4.z * w4.z + q4.w * w4.w;
        }
        qbias_g[b * Hh + t] = acc + bg[t];
    }
}

// ---------------- Fused scores GEMM v6: W-in-regs + A via global_load_lds,
// 4-buffer / 3-tiles-ahead / ONE barrier per iteration, pure-read pipeline.
// Grid = 512 blocks x 512 threads (8 waves), 2 blocks/CU.
// Wave w holds W n-slice [w*32,w*32+32) in regs (bfrag[2][8]=64 VGPR).
// Block owns 256 rows = 16 tiles of 16 rows; tile tt lives in Abuf[tt&3]
// (fragment order [region][lane][16B], linear lane scatter, conflict-free reads).
// Iter tt: WAITVM(2I) retires exactly tile tt's own loads (3 tiles remain in
// flight; tails: I at tt=14, 0 at tt=15) -> s_barrier (all waves' tile-tt data
// visible) -> stage(tt+3) into buf (tt+3)&3 (safe: every wave passed this barrier
// after finishing compute(tt-1), max skew < 1 iter) -> ds_read + cvt_pk + 16 MFMA
// + tanh*v + shfl-reduce into wave-exclusive partial slot. NO stores in the loop
// (side-output moved to glimpse_part: stores would poison in-order vmcnt counting).
template <int MASKED, int LOADF32>
__global__ __launch_bounds__(512, 2) void scores_mfma(const float* __restrict__ reff,
                                                      const short* __restrict__ refb_in,
                                                      const short* __restrict__ Wbf,
                                                      const float* __restrict__ qbias,
                                                      const float* __restrict__ vvec,
                                                      const int* __restrict__ mask,
                                                      float* __restrict__ out) {
    constexpr int TS = LOADF32 ? 8192 : 4096;  // shorts per tile buffer
    constexpr int I = LOADF32 ? 2 : 1;         // stage instr per tile per wave
    __shared__ __align__(16) short Abuf[4][TS];
    __shared__ float partial[8][256];
    const int t = threadIdx.x;
    const int w = t >> 6;
    const int lane = t & 63;
    const int nl = lane & 15;
    const int quad = lane >> 4;
    const int b = blockIdx.x >> 2;
    const int row0 = (blockIdx.x & 3) * 256;

    // persistent W fragments first (their vmcnt slots retire before the pipeline fills)
    bf16x8 bfrag[2][8];
#pragma unroll
    for (int nc2 = 0; nc2 < 2; ++nc2) {
        const short* wpr = Wbf + (w * 32 + nc2 * 16 + nl) * Hh + quad * 8;
#pragma unroll
        for (int kb = 0; kb < 8; ++kb)
            bfrag[nc2][kb] = *(const bf16x8*)(wpr + kb * 32);
    }
    const float qb0 = qbias[b * Hh + w * 32 + nl];
    const float qb1 = qbias[b * Hh + w * 32 + 16 + nl];
    const float vv0 = vvec[w * 32 + nl];
    const float vv1 = vvec[w * 32 + 16 + nl];

    // stage tile tt: wave w supplies k-cols [w*32, w*32+32)
    // lane l -> row nl=l&15, cols w*32+(l>>4)*8 (+4 for fp32 second half)
    auto stage_tile = [&](int tt, int buf) {
        if (LOADF32) {
            const float* g = reff + ((size_t)b * Ss + row0 + tt * 16 + nl) * Hh + w * 32 + quad * 8;
            stage16(g,     &Abuf[buf][(w * 2 + 0) * 512]);
            stage16(g + 4, &Abuf[buf][(w * 2 + 1) * 512]);
        } else {
            const short* g = refb_in + ((size_t)b * Ss + row0 + tt * 16 + nl) * Hh + w * 32 + quad * 8;
            stage16(g, &Abuf[buf][w * 512]);
        }
    };

    stage_tile(0, 0);
    stage_tile(1, 1);
    stage_tile(2, 2);

#pragma unroll 1
    for (int tt = 0; tt < 16; ++tt) {
        // retire exactly tile tt's own loads; keep 2 (tail: 1, 0) tiles in flight
        if (tt <= 13)      WAITVM(2 * I)
        else if (tt == 14) WAITVM(I)
        else               WAITVM(0)
        __builtin_amdgcn_s_barrier();          // all waves' tile-tt data now in LDS
        __builtin_amdgcn_sched_barrier(0);
        if (tt <= 12) stage_tile(tt + 3, (tt + 3) & 3);

        const short* bufp = Abuf[tt & 3];
        f32x4 c0 = {0.f, 0.f, 0.f, 0.f};
        f32x4 c1 = {0.f, 0.f, 0.f, 0.f};
#pragma unroll
        for (int kb = 0; kb < 8; ++kb) {
            bf16x8 af;
            if (LOADF32) {
                float4 lo = *(const float4*)&bufp[(kb * 2 + 0) * 512 + lane * 8];
                float4 hi = *(const float4*)&bufp[(kb * 2 + 1) * 512 + lane * 8];
                union { unsigned u[4]; bf16x8 v; } cv;
                cv.u[0] = cvt_pk_bf16(lo.x, lo.y);
                cv.u[1] = cvt_pk_bf16(lo.z, lo.w);
                cv.u[2] = cvt_pk_bf16(hi.x, hi.y);
                cv.u[3] = cvt_pk_bf16(hi.z, hi.w);
                af = cv.v;
            } else {
                af = *(const bf16x8*)&bufp[kb * 512 + lane * 8];
            }
            c0 = __builtin_amdgcn_mfma_f32_16x16x32_bf16(af, bfrag[0][kb], c0, 0, 0, 0);
            c1 = __builtin_amdgcn_mfma_f32_16x16x32_bf16(af, bfrag[1][kb], c1, 0, 0, 0);
        }
        // C/D: col = lane&15 (n-lane), row = quad*4 + r ; reduce over 16 n-lanes
#pragma unroll
        for (int r = 0; r < 4; ++r) {
            float s = fast_tanh(c0[r] + qb0) * vv0 + fast_tanh(c1[r] + qb1) * vv1;
            s += __shfl_xor(s, 1, 64);
            s += __shfl_xor(s, 2, 64);
            s += __shfl_xor(s, 4, 64);
            s += __shfl_xor(s, 8, 64);
            if (nl == 0) partial[w][tt * 16 + quad * 4 + r] = s;
        }
    }

    __syncthreads();
    if (t < 256) {
        float s = 0.f;
#pragma unroll
        for (int g = 0; g < 8; ++g) s += partial[g][t];
        if (MASKED) s -= (float)mask[b * Ss + row0 + t] * NEGF;
        out[(size_t)b * Ss + row0 + t] = s;
    }
}

// ---------------- Softmax over S per batch (mask applied) -> att ----------------
__global__ __launch_bounds__(1024) void softmax_kernel(const float* __restrict__ scores,
                                                       const int* __restrict__ mask,
                                                       float* __restrict__ att) {
    int b = blockIdx.x, t = threadIdx.x;
    __shared__ float red[16];
    int idx = b * Ss + t;
    float x = scores[idx] - (float)mask[idx] * NEGF;

    float m = x;
#pragma unroll
    for (int o = 1; o < 64; o <<= 1) m = fmaxf(m, __shfl_xor(m, o, 64));
    if ((t & 63) == 0) red[t >> 6] = m;
    __syncthreads();
    float M = red[0];
#pragma unroll
    for (int j = 1; j < 16; ++j) M = fmaxf(M, red[j]);
    __syncthreads();

    float e = __expf(x - M);
    float s = e;
#pragma unroll
    for (int o = 1; o < 64; o <<= 1) s += __shfl_xor(s, o, 64);
    if ((t & 63) == 0) red[t >> 6] = s;
    __syncthreads();
    float S = 0.f;
#pragma unroll
    for (int j = 0; j < 16; ++j) S += red[j];

    att[idx] = e * __builtin_amdgcn_rcpf(S);
}

// ---------------- Glimpse partial + ref->bf16 convert (fused streaming pass):
// gpart[b,q,d] = sum_{s in 1/8th q} att*ref  (fp32 ref: more accurate than bf16)
// side-output: ref_bf = bf16(ref) for pass 2 (plain streaming stores -- no
// counted-vmcnt protocol here, so stores are harmless)
__global__ __launch_bounds__(256) void glimpse_part(const float* __restrict__ reff,
                                                    const float* __restrict__ att,
                                                    short* __restrict__ refb_out,
                                                    float* __restrict__ gpart) {
    int b = blockIdx.x, q = blockIdx.y, t = threadIdx.x;
    const int c = t & 31;      // 32B chunk: d = c*8 .. c*8+7
    const int rg = t >> 5;     // row group 0..7
    __shared__ float part[8][Hh];
    const float* base = reff + ((size_t)(b * Ss + q * 128)) * Hh;
    short* outb = refb_out + ((size_t)(b * Ss + q * 128)) * Hh;
    const float* ap = att + b * Ss + q * 128;

    float acc[8] = {0.f, 0.f, 0.f, 0.f, 0.f, 0.f, 0.f, 0.f};
#pragma unroll 4
    for (int it = 0; it < 16; ++it) {
        int row = it * 8 + rg;
        float a = ap[row];
        const float4* rp = (const float4*)(base + (size_t)row * Hh + c * 8);
        float4 lo = rp[0], hi = rp[1];
        acc[0] += a * lo.x; acc[1] += a * lo.y; acc[2] += a * lo.z; acc[3] += a * lo.w;
        acc[4] += a * hi.x; acc[5] += a * hi.y; acc[6] += a * hi.z; acc[7] += a * hi.w;
        union { unsigned u[4]; bf16x8 v; } cv;
        cv.u[0] = cvt_pk_bf16(lo.x, lo.y);
        cv.u[1] = cvt_pk_bf16(lo.z, lo.w);
        cv.u[2] = cvt_pk_bf16(hi.x, hi.y);
        cv.u[3] = cvt_pk_bf16(hi.z, hi.w);
        *(bf16x8*)(outb + (size_t)row * Hh + c * 8) = cv.v;
    }
#pragma unroll
    for (int j = 0; j < 8; ++j) part[rg][c * 8 + j] = acc[j];
    __syncthreads();
    float s = 0.f;
#pragma unroll
    for (int g = 0; g < 8; ++g) s += part[g][t];
    gpart[(size_t)(b * 8 + q) * Hh + t] = s;
}

// ---------------- qbias_p[b,h] = sum_d glimpse[b,d]*wqp[h,d] + bp[h] ------------
__global__ __launch_bounds__(256) void qbias_p_kernel(const float* __restrict__ gpart,
                                                      const float* __restrict__ query,
                                                      const float* __restrict__ wqp,
                                                      const float* __restrict__ bp,
                                                      float* __restrict__ out) {
    int b = blockIdx.x, t = threadIdx.x;
    __shared__ __align__(16) float gl[Hh];
    float g = query[b * Hh + t];
#pragma unroll
    for (int q = 0; q < 8; ++q) g += gpart[(b * 8 + q) * Hh + t];
    gl[t] = g;
    __syncthreads();
    const float4* wr = (const float4*)(wqp + t * Hh);
    const float4* gp = (const float4*)gl;
    float acc = 0.f;
#pragma unroll 8
    for (int i = 0; i < Hh / 4; ++i) {
        float4 w4 = wr[i];
        float4 g4 = gp[i];
        acc += w4.x * g4.x + w4.y * g4.y + w4.z * g4.z + w4.w * g4.w;
    }
    out[b * Hh + t] = acc + bp[t];
}

extern "C" void kernel_launch(void* const* d_in, const int* in_sizes, int n_in,
                              void* d_out, int out_size, void* d_ws, size_t ws_size,
                              hipStream_t stream) {
    const float* ref   = (const float*)d_in[0];
    const float* query = (const float*)d_in[1];
    const int*   mask  = (const int*)d_in[2];
    const float* wg    = (const float*)d_in[3];
    const float* bg    = (const float*)d_in[4];
    const float* wqg   = (const float*)d_in[5];
    const float* vg    = (const float*)d_in[6];
    const float* wp    = (const float*)d_in[7];
    const float* bp    = (const float*)d_in[8];
    const float* wqp   = (const float*)d_in[9];
    const float* vp    = (const float*)d_in[10];
    float* out = (float*)d_out;

    char* ws = (char*)d_ws;
    short* ref_bf   = (short*)(ws + 0);          // 64 MB (B*S*H bf16)
    size_t off = (size_t)Bb * Ss * Hh * 2;
    short* wg_bf    = (short*)(ws + off);               off += 131072;
    short* wp_bf    = (short*)(ws + off);               off += 131072;
    float* qbias_g  = (float*)(ws + off);               off += 131072;
    float* qbias_p  = (float*)(ws + off);               off += 131072;
    float* scores_g = (float*)(ws + off);               off += 524288;
    float* att      = (float*)(ws + off);               off += 524288;
    float* gpart    = (float*)(ws + off);               // 1 MB

    prep_kernel<<<384, 256, 0, stream>>>(wg, wp, query, wqg, bg, wg_bf, wp_bf, qbias_g);
    // glimpse scores: fp32 ref in, pure-read pipeline; unmasked (softmax applies mask)
    scores_mfma<0, 1><<<512, 512, 0, stream>>>(
        ref, nullptr, wg_bf, qbias_g, vg, nullptr, scores_g);
    softmax_kernel<<<Bb, Ss, 0, stream>>>(scores_g, mask, att);
    // glimpse partial from fp32 ref, fused ref->bf16 convert for pass 2
    glimpse_part<<<dim3(Bb, 8), 256, 0, stream>>>(ref, att, ref_bf, gpart);
    qbias_p_kernel<<<Bb, Hh, 0, stream>>>(gpart, query, wqp, bp, qbias_p);
    // pointer scores: bf16 ref in, masked, straight to d_out
    scores_mfma<1, 0><<<512, 512, 0, stream>>>(
        nullptr, ref_bf, wp_bf, qbias_p, vp, mask, out);
}

// Round 7
// 303.644 us; speedup vs baseline: 1.0023x; 1.0023x over previous
//
#include <hip/hip_runtime.h>

// B=128, S=1024, H=256
#define Bb 128
#define Ss 1024
#define Hh 256
#define NEGF 1e9f

typedef short bf16x8 __attribute__((ext_vector_type(8)));
typedef float f32x4 __attribute__((ext_vector_type(4)));

__device__ __forceinline__ short f2bf(float f) {
    union { float f; unsigned u; } c; c.f = f;
    return (short)((c.u + 0x8000u) >> 16);
}

// packed fp32->bf16 (RNE), 1 instr per 2 elements
__device__ __forceinline__ unsigned cvt_pk_bf16(float a, float b) {
    unsigned r;
    asm("v_cvt_pk_bf16_f32 %0, %1, %2" : "=v"(r) : "v"(a), "v"(b));
    return r;
}

__device__ __forceinline__ float fast_tanh(float x) {
    float cl = fminf(fmaxf(x, -10.f), 10.f);
    float e = __expf(2.f * cl);
    return (e - 1.f) * __builtin_amdgcn_rcpf(e + 1.f);
}

// async global->LDS, 16B per lane; dest = (wave-uniform) lds base + lane*16
__device__ __forceinline__ void stage16(const void* g, short* l) {
    __builtin_amdgcn_global_load_lds((const __attribute__((address_space(1))) void*)g,
                                     (__attribute__((address_space(3))) void*)l, 16, 0, 0);
}

// counted vmcnt wait: gfx9 encoding vm[3:0]|exp[6:4]|lgkm[11:8] (exp,lgkm = no-wait)
#define WAITVM(N) { __builtin_amdgcn_s_waitcnt(0x0F70 | (N)); __builtin_amdgcn_sched_barrier(0); }

// ---------------- prep: wg,wp -> bf16 (blocks 0..255); qbias_g (blocks 256..383)
__global__ __launch_bounds__(256) void prep_kernel(const float* __restrict__ wg,
                                                   const float* __restrict__ wp,
                                                   const float* __restrict__ query,
                                                   const float* __restrict__ wqg,
                                                   const float* __restrict__ bg,
                                                   short* __restrict__ wgb,
                                                   short* __restrict__ wpb,
                                                   float* __restrict__ qbias_g) {
    int blk = blockIdx.x, t = threadIdx.x;
    if (blk < 256) {
        int i = blk * 256 + t;
        wgb[i] = f2bf(wg[i]);
        wpb[i] = f2bf(wp[i]);
    } else {
        int b = blk - 256;
        const float4* qr = (const float4*)(query + b * Hh);
        const float4* wr = (const float4*)(wqg + t * Hh);
        float acc = 0.f;
#pragma unroll 8
        for (int i = 0; i < Hh / 4; ++i) {
            float4 q4 = qr[i], w4 = wr[i];
            acc += q4.x * w4.x + q4.y * w4.y + q4.z * w4.z + q4.w * w4.w;
        }
        qbias_g[b * Hh + t] = acc + bg[t];
    }
}

// ---------------- Fused scores GEMM v7: W-in-regs + fp32 A via global_load_lds with
// single-convert bf16 share stage. Grid = 512 x 512 (8 waves), 2 blocks/CU (64 KB LDS).
// Wave w holds W n-slice [w*32,w*32+32) in regs (bfrag[2][8]=64 VGPR).
// Block owns 256 rows = 16 tiles of 16 rows.
// Per tile: each wave gload_lds's ONLY ITS OWN 32 fp32 columns (2x16B/lane) into
// F32buf; since only wave w ever touches that slice, retiring its OWN vmcnt is
// enough to convert (ds_read fp32 x2 + 4 cvt_pk + ds_write bf16 x1, all linear
// lane*16B, conflict-free) -- NO barrier for the convert. All 8 waves then read
// the shared bf16 tile (8x ds_read_b128 each). LDS read volume: 2.25 MB/CU/pass
// (vs v6's 4 MB fp32-redundant), convert done once instead of 8x.
// Pipeline (1 barrier/iter): a) gload fp32(tt+2) into F32buf[tt&1] (freed: own
// convert read of it was drained by lgkmcnt(0) last iter); b) WAITVM(2) [own
// fp32(tt+1) landed; (tt+2)'s 2 ops stay in flight] + convert(tt+1)->Bbuf[(tt+1)%3];
// c) lgkmcnt(0)+s_barrier [bf16(tt+1) visible to all next iter; max skew <1 iter
// => writer hits (tt+2)%3 while slowest reader is on tt%3 -- distinct mod 3];
// d) compute(tt) from Bbuf[tt%3]: 16 MFMA + tanh*v + shfl-reduce into partial[w].
template <int MASKED>
__global__ __launch_bounds__(512, 2) void scores_mfma(const float* __restrict__ reff,
                                                      const short* __restrict__ Wbf,
                                                      const float* __restrict__ qbias,
                                                      const float* __restrict__ vvec,
                                                      const int* __restrict__ mask,
                                                      float* __restrict__ out) {
    __shared__ __align__(16) short F32buf[2][8192];  // 2 x 16 KB fp32 tiles
    __shared__ __align__(16) short Bbuf[3][4096];    // 3 x 8 KB bf16 tiles
    __shared__ float partial[8][256];                // 8 KB
    const int t = threadIdx.x;
    const int w = t >> 6;
    const int lane = t & 63;
    const int nl = lane & 15;
    const int quad = lane >> 4;
    const int b = blockIdx.x >> 2;
    const int row0 = (blockIdx.x & 3) * 256;

    // persistent W fragments (issued first; oldest vmcnt slots, retired by prologue wait)
    bf16x8 bfrag[2][8];
#pragma unroll
    for (int nc2 = 0; nc2 < 2; ++nc2) {
        const short* wpr = Wbf + (w * 32 + nc2 * 16 + nl) * Hh + quad * 8;
#pragma unroll
        for (int kb = 0; kb < 8; ++kb)
            bfrag[nc2][kb] = *(const bf16x8*)(wpr + kb * 32);
    }
    const float qb0 = qbias[b * Hh + w * 32 + nl];
    const float qb1 = qbias[b * Hh + w * 32 + 16 + nl];
    const float vv0 = vvec[w * 32 + nl];
    const float vv1 = vvec[w * 32 + 16 + nl];

    // gload fp32 tile tt (wave w's own cols [w*32,w*32+32)) into F32buf[f]
    // lane l: row nl=l&15, cols w*32+quad*8 (+4); dest linear lane*16B per region
    auto stage = [&](int tt, int f) {
        const float* g = reff + ((size_t)b * Ss + row0 + tt * 16 + nl) * Hh + w * 32 + quad * 8;
        stage16(g,     &F32buf[f][(w * 2 + 0) * 512]);
        stage16(g + 4, &F32buf[f][(w * 2 + 1) * 512]);
    };
    // convert own slice from F32buf[f] -> Bbuf[bb] (fragment order: kb=w slice is
    // shorts [w*512, w*512+512), lane l at w*512 + l*8 = row(l&15), col w*32+(l>>4)*8)
    auto convert = [&](int f, int bb) {
        float4 lo = *(const float4*)&F32buf[f][(w * 2 + 0) * 512 + lane * 8];
        float4 hi = *(const float4*)&F32buf[f][(w * 2 + 1) * 512 + lane * 8];
        union { unsigned u[4]; bf16x8 v; } cv;
        cv.u[0] = cvt_pk_bf16(lo.x, lo.y);
        cv.u[1] = cvt_pk_bf16(lo.z, lo.w);
        cv.u[2] = cvt_pk_bf16(hi.x, hi.y);
        cv.u[3] = cvt_pk_bf16(hi.z, hi.w);
        *(bf16x8*)&Bbuf[bb][w * 512 + lane * 8] = cv.v;
    };

    stage(0, 0);
    stage(1, 1);
    WAITVM(2)                 // own fp32(0) landed (also retires older W loads)
    convert(0, 0);
    asm volatile("s_waitcnt lgkmcnt(0)" ::: "memory");
    __builtin_amdgcn_s_barrier();
    __builtin_amdgcn_sched_barrier(0);

#pragma unroll 1
    for (int tt = 0; tt < 16; ++tt) {
        if (tt <= 13) stage(tt + 2, tt & 1);
        if (tt <= 14) {
            if (tt <= 13) WAITVM(2) else WAITVM(0)
            convert((tt + 1) & 1, (tt + 1) % 3);
        }
        asm volatile("s_waitcnt lgkmcnt(0)" ::: "memory");
        __builtin_amdgcn_s_barrier();
        __builtin_amdgcn_sched_barrier(0);

        const short* bufp = Bbuf[tt % 3];
        f32x4 c0 = {0.f, 0.f, 0.f, 0.f};
        f32x4 c1 = {0.f, 0.f, 0.f, 0.f};
#pragma unroll
        for (int kb = 0; kb < 8; ++kb) {
            bf16x8 af = *(const bf16x8*)&bufp[kb * 512 + lane * 8];
            c0 = __builtin_amdgcn_mfma_f32_16x16x32_bf16(af, bfrag[0][kb], c0, 0, 0, 0);
            c1 = __builtin_amdgcn_mfma_f32_16x16x32_bf16(af, bfrag[1][kb], c1, 0, 0, 0);
        }
        // C/D: col = lane&15 (n-lane), row = quad*4 + r ; reduce over 16 n-lanes
#pragma unroll
        for (int r = 0; r < 4; ++r) {
            float s = fast_tanh(c0[r] + qb0) * vv0 + fast_tanh(c1[r] + qb1) * vv1;
            s += __shfl_xor(s, 1, 64);
            s += __shfl_xor(s, 2, 64);
            s += __shfl_xor(s, 4, 64);
            s += __shfl_xor(s, 8, 64);
            if (nl == 0) partial[w][tt * 16 + quad * 4 + r] = s;
        }
    }

    __syncthreads();
    if (t < 256) {
        float s = 0.f;
#pragma unroll
        for (int g = 0; g < 8; ++g) s += partial[g][t];
        if (MASKED) s -= (float)mask[b * Ss + row0 + t] * NEGF;
        out[(size_t)b * Ss + row0 + t] = s;
    }
}

// ---------------- Softmax over S per batch (mask applied) -> att ----------------
__global__ __launch_bounds__(1024) void softmax_kernel(const float* __restrict__ scores,
                                                       const int* __restrict__ mask,
                                                       float* __restrict__ att) {
    int b = blockIdx.x, t = threadIdx.x;
    __shared__ float red[16];
    int idx = b * Ss + t;
    float x = scores[idx] - (float)mask[idx] * NEGF;

    float m = x;
#pragma unroll
    for (int o = 1; o < 64; o <<= 1) m = fmaxf(m, __shfl_xor(m, o, 64));
    if ((t & 63) == 0) red[t >> 6] = m;
    __syncthreads();
    float M = red[0];
#pragma unroll
    for (int j = 1; j < 16; ++j) M = fmaxf(M, red[j]);
    __syncthreads();

    float e = __expf(x - M);
    float s = e;
#pragma unroll
    for (int o = 1; o < 64; o <<= 1) s += __shfl_xor(s, o, 64);
    if ((t & 63) == 0) red[t >> 6] = s;
    __syncthreads();
    float S = 0.f;
#pragma unroll
    for (int j = 0; j < 16; ++j) S += red[j];

    att[idx] = e * __builtin_amdgcn_rcpf(S);
}

// ---------------- Glimpse partial (fp32 ref, L3-hot after pass 1):
// gpart[b,q,d] = sum_{s in 1/8th q} att*ref
__global__ __launch_bounds__(256) void glimpse_part(const float* __restrict__ reff,
                                                    const float* __restrict__ att,
                                                    float* __restrict__ gpart) {
    int b = blockIdx.x, q = blockIdx.y, t = threadIdx.x;
    const int c = t & 31;      // 32B chunk: d = c*8 .. c*8+7
    const int rg = t >> 5;     // row group 0..7
    __shared__ float part[8][Hh];
    const float* base = reff + ((size_t)(b * Ss + q * 128)) * Hh;
    const float* ap = att + b * Ss + q * 128;

    float acc[8] = {0.f, 0.f, 0.f, 0.f, 0.f, 0.f, 0.f, 0.f};
#pragma unroll 4
    for (int it = 0; it < 16; ++it) {
        int row = it * 8 + rg;
        float a = ap[row];
        const float4* rp = (const float4*)(base + (size_t)row * Hh + c * 8);
        float4 lo = rp[0], hi = rp[1];
        acc[0] += a * lo.x; acc[1] += a * lo.y; acc[2] += a * lo.z; acc[3] += a * lo.w;
        acc[4] += a * hi.x; acc[5] += a * hi.y; acc[6] += a * hi.z; acc[7] += a * hi.w;
    }
#pragma unroll
    for (int j = 0; j < 8; ++j) part[rg][c * 8 + j] = acc[j];
    __syncthreads();
    float s = 0.f;
#pragma unroll
    for (int g = 0; g < 8; ++g) s += part[g][t];
    gpart[(size_t)(b * 8 + q) * Hh + t] = s;
}

// ---------------- qbias_p[b,h] = sum_d glimpse[b,d]*wqp[h,d] + bp[h] ------------
__global__ __launch_bounds__(256) void qbias_p_kernel(const float* __restrict__ gpart,
                                                      const float* __restrict__ query,
                                                      const float* __restrict__ wqp,
                                                      const float* __restrict__ bp,
                                                      float* __restrict__ out) {
    int b = blockIdx.x, t = threadIdx.x;
    __shared__ __align__(16) float gl[Hh];
    float g = query[b * Hh + t];
#pragma unroll
    for (int q = 0; q < 8; ++q) g += gpart[(b * 8 + q) * Hh + t];
    gl[t] = g;
    __syncthreads();
    const float4* wr = (const float4*)(wqp + t * Hh);
    const float4* gp = (const float4*)gl;
    float acc = 0.f;
#pragma unroll 8
    for (int i = 0; i < Hh / 4; ++i) {
        float4 w4 = wr[i];
        float4 g4 = gp[i];
        acc += w4.x * g4.x + w4.y * g4.y + w4.z * g4.z + w4.w * g4.w;
    }
    out[b * Hh + t] = acc + bp[t];
}

extern "C" void kernel_launch(void* const* d_in, const int* in_sizes, int n_in,
                              void* d_out, int out_size, void* d_ws, size_t ws_size,
                              hipStream_t stream) {
    const float* ref   = (const float*)d_in[0];
    const float* query = (const float*)d_in[1];
    const int*   mask  = (const int*)d_in[2];
    const float* wg    = (const float*)d_in[3];
    const float* bg    = (const float*)d_in[4];
    const float* wqg   = (const float*)d_in[5];
    const float* vg    = (const float*)d_in[6];
    const float* wp    = (const float*)d_in[7];
    const float* bp    = (const float*)d_in[8];
    const float* wqp   = (const float*)d_in[9];
    const float* vp    = (const float*)d_in[10];
    float* out = (float*)d_out;

    char* ws = (char*)d_ws;
    size_t off = 0;
    short* wg_bf    = (short*)(ws + off);               off += 131072;
    short* wp_bf    = (short*)(ws + off);               off += 131072;
    float* qbias_g  = (float*)(ws + off);               off += 131072;
    float* qbias_p  = (float*)(ws + off);               off += 131072;
    float* scores_g = (float*)(ws + off);               off += 524288;
    float* att      = (float*)(ws + off);               off += 524288;
    float* gpart    = (float*)(ws + off);               // 1 MB

    prep_kernel<<<384, 256, 0, stream>>>(wg, wp, query, wqg, bg, wg_bf, wp_bf, qbias_g);
    // glimpse scores (unmasked; softmax applies mask)
    scores_mfma<0><<<512, 512, 0, stream>>>(ref, wg_bf, qbias_g, vg, nullptr, scores_g);
    softmax_kernel<<<Bb, Ss, 0, stream>>>(scores_g, mask, att);
    // glimpse partial from fp32 ref (L3-resident after pass 1)
    glimpse_part<<<dim3(Bb, 8), 256, 0, stream>>>(ref, att, gpart);
    qbias_p_kernel<<<Bb, Hh, 0, stream>>>(gpart, query, wqp, bp, qbias_p);
    // pointer scores: masked, straight to d_out
    scores_mfma<1><<<512, 512, 0, stream>>>(ref, wp_bf, qbias_p, vp, mask, out);
}